// Round 12
// baseline (64.707 us; speedup 1.0000x reference)
//
#include <hip/hip_runtime.h>

// GE2E loss, N=1024 spk, M=32 utt, D=512.
// v12: fp8 GEMM, TLP (3 blocks/CU) + ring-3 counted-vmcnt + 0-conflict b128.
// prep: e8 = fp8(8*emb), ck8 = fp8(16*sgn(lw)*ck), both stored with each
// 64-byte K-group byte-permuted: byte k -> (k&~63) + ((k>>3)&3)*16 +
// ((k>>5)&1)*8, so one 16B chunk = {kk0 octet c, kk1 octet c} (same perm on
// A and B => dot product invariant). gemm: 2048 blocks of 128x128, 4 waves
// (64x64 each); LDS ring of 3 x 16 KB; stage(t+2) at tile start via
// global_load_lds (pre-swizzled source); ONE barrier + vmcnt(4) per K-tile
// (issue->gate distance = 1 full tile; never 0 until tail). Fragment read =
// 1 ds_read_b128 per frag with the r6/r10 measured-0-conflict XOR pattern.
// sims scaled x128*sgn; /128 folded into rowred.

#define N_SPK 1024
#define M_UTT 32
#define D_DIM 512
#define NROWS (N_SPK * M_UTT)   // 32768
#define NTILES 8                // 1024/128 col tiles
#define MTILES 256              // 32768/128 row tiles
#define NWG (MTILES * NTILES)   // 2048
#define NKT 8                   // 512/64

typedef __attribute__((ext_vector_type(4))) float f32x4;
typedef __attribute__((ext_vector_type(2))) long long2v;   // 16 B

__device__ __forceinline__ void gload_lds16(const void* g, void* l) {
    __builtin_amdgcn_global_load_lds(
        (const __attribute__((address_space(1))) unsigned int*)g,
        (__attribute__((address_space(3))) unsigned int*)l, 16, 0, 0);
}

__device__ __forceinline__ float sigmoidf(float x) {
    return 1.f / (1.f + __expf(-x));
}

// ---- k1: e8 = fp8(8*emb), ck8 = fp8(16*sgn(lw)*ck), k-permuted -------------
__global__ void __launch_bounds__(256) prep_kernel(const float* __restrict__ emb,
                                                   const float* __restrict__ lnw,
                                                   char* __restrict__ e8,
                                                   char* __restrict__ ck8) {
    __shared__ float part[4][D_DIM];
    const int n = blockIdx.x;
    const int t = threadIdx.x;
    const int q = t & 63;          // octet index within row (k = q*8)
    const int g = t >> 6;          // row group (8 rows each)
    // permuted dest byte offset of octet q
    const int pdst = (q >> 3) * 64 + (q & 3) * 16 + ((q >> 2) & 1) * 8;
    const float* base = emb + (size_t)n * M_UTT * D_DIM + q * 8;

    float acc8[8];
#pragma unroll
    for (int j = 0; j < 8; ++j) acc8[j] = 0.f;

#pragma unroll
    for (int i = 0; i < 8; ++i) {
        const int m = g * 8 + i;
        const float4 v0 = *reinterpret_cast<const float4*>(base + m * D_DIM);
        const float4 v1 = *reinterpret_cast<const float4*>(base + m * D_DIM + 4);
        acc8[0] += v0.x; acc8[1] += v0.y; acc8[2] += v0.z; acc8[3] += v0.w;
        acc8[4] += v1.x; acc8[5] += v1.y; acc8[6] += v1.z; acc8[7] += v1.w;
        int w0 = __builtin_amdgcn_cvt_pk_fp8_f32(8.f * v0.x, 8.f * v0.y, 0, false);
        w0 = __builtin_amdgcn_cvt_pk_fp8_f32(8.f * v0.z, 8.f * v0.w, w0, true);
        int w1 = __builtin_amdgcn_cvt_pk_fp8_f32(8.f * v1.x, 8.f * v1.y, 0, false);
        w1 = __builtin_amdgcn_cvt_pk_fp8_f32(8.f * v1.z, 8.f * v1.w, w1, true);
        uint2 w; w.x = (unsigned)w0; w.y = (unsigned)w1;
        *reinterpret_cast<uint2*>(e8 + (size_t)(n * M_UTT + m) * D_DIM + pdst) = w;
    }
#pragma unroll
    for (int j = 0; j < 8; ++j) part[g][q * 8 + j] = acc8[j];
    __syncthreads();

    if (t < 64) {
        const float sc = (lnw[0] >= 0.f) ? 0.5f : -0.5f;   // 16*sgn/32
        float s[8];
#pragma unroll
        for (int j = 0; j < 8; ++j)
            s[j] = (part[0][t * 8 + j] + part[1][t * 8 + j] +
                    part[2][t * 8 + j] + part[3][t * 8 + j]) * sc;
        int w0 = __builtin_amdgcn_cvt_pk_fp8_f32(s[0], s[1], 0, false);
        w0 = __builtin_amdgcn_cvt_pk_fp8_f32(s[2], s[3], w0, true);
        int w1 = __builtin_amdgcn_cvt_pk_fp8_f32(s[4], s[5], 0, false);
        w1 = __builtin_amdgcn_cvt_pk_fp8_f32(s[6], s[7], w1, true);
        uint2 w; w.x = (unsigned)w0; w.y = (unsigned)w1;
        const int pd = (t >> 3) * 64 + (t & 3) * 16 + ((t >> 2) & 1) * 8;
        *reinterpret_cast<uint2*>(ck8 + (size_t)n * D_DIM + pd) = w;
    }
}

// ---- k2: fp8 GEMM, 128x128 blocks, ring-3, counted vmcnt -------------------
__global__ void __launch_bounds__(256, 3)
gemm_kernel(const char* __restrict__ e8,
            const char* __restrict__ ck8,
            float* __restrict__ maxo_part,
            float* __restrict__ own_part) {
    // buf[slot]: A 128x64B at [0,8192), B at [8192,16384).
    // line L (128B) = rows {2L,2L+1}; logical chunk l = (row&1)*4 + c,
    // stored at phys = l ^ (L&7). Chunk c of a row = {kk0 octet c, kk1 octet c}
    // (from the prep permutation).
    __shared__ __align__(16) char buf[3][16384];   // 48 KB
    __shared__ float redm[2][128];                 // 1 KB
    __shared__ float redo[2][128];

    const int tid  = threadIdx.x;
    const int lane = tid & 63;
    const int wv   = tid >> 6;
    const int lo   = lane & 15;
    const int hi   = lane >> 4;
    const int wm   = wv >> 1;   // 0..1 : 64-row half
    const int wn   = wv & 1;    // 0..1 : 64-col half

    // XCD map: xcd gets 32 consecutive mt x all 8 nt (A 2MB + ck 0.5MB in L2)
    const int raw   = blockIdx.x;
    const int xcd   = raw & 7;
    const int local = raw >> 3;              // 0..255
    const int mt    = xcd * 32 + (local >> 3);
    const int nt    = local & 7;
    const int r0    = mt * 128;
    const int n0    = nt * 128;

    // ---- staging map: 512 16B-chunks per region, 2 per thread ----
    const char* pA[2];
    const char* pB[2];
    int dA[2], dB[2];
#pragma unroll
    for (int j = 0; j < 2; ++j) {
        const int s   = j * 256 + tid;
        const int L   = s >> 3;
        const int l   = (s & 7) ^ (L & 7);
        const int row = 2 * L + (l >> 2);
        const int c   = l & 3;
        pA[j] = e8  + (size_t)(r0 + row) * D_DIM + c * 16;
        pB[j] = ck8 + (size_t)(n0 + row) * D_DIM + c * 16;
        dA[j] = s * 16;
        dB[j] = 8192 + s * 16;
    }

    auto stage = [&](int u, int slot) {
        char* bb = &buf[slot][0];
        const int ko = u * 64;
#pragma unroll
        for (int j = 0; j < 2; ++j) {
            gload_lds16(pA[j] + ko, bb + dA[j]);
            gload_lds16(pB[j] + ko, bb + dB[j]);
        }
    };

    // prologue: tiles 0,1 in flight; gate tile 0 only
    stage(0, 0);
    stage(1, 1);
    asm volatile("s_waitcnt vmcnt(4)" ::: "memory");
    __builtin_amdgcn_s_barrier();

    // ---- fragment read addressing (one b128 per frag, r6-pattern) ----
    const int swz   = (lo >> 1) & 7;
    const int par   = lo & 1;
    const int physr = ((par << 2) | hi) ^ swz;
    const int abase = (wm * 32 + (lo >> 1)) * 128 + physr * 16;
    const int bbase = 8192 + (wn * 32 + (lo >> 1)) * 128 + physr * 16;

    f32x4 acc[4][4];
#pragma unroll
    for (int am = 0; am < 4; ++am)
#pragma unroll
        for (int an = 0; an < 4; ++an) acc[am][an] = (f32x4){0.f, 0.f, 0.f, 0.f};

#pragma unroll
    for (int t = 0; t < NKT; ++t) {
        const char* bp = &buf[t % 3][0];
        if (t + 2 < NKT) stage(t + 2, (t + 2) % 3);

        long2v a2[4], b2[4];
#pragma unroll
        for (int am = 0; am < 4; ++am)
            a2[am] = *reinterpret_cast<const long2v*>(bp + abase + am * 1024);
#pragma unroll
        for (int an = 0; an < 4; ++an)
            b2[an] = *reinterpret_cast<const long2v*>(bp + bbase + an * 1024);

        __builtin_amdgcn_s_setprio(1);
#pragma unroll
        for (int am = 0; am < 4; ++am)
#pragma unroll
            for (int an = 0; an < 4; ++an)
                acc[am][an] = __builtin_amdgcn_mfma_f32_16x16x32_fp8_fp8(
                    a2[am][0], b2[an][0], acc[am][an], 0, 0, 0);
#pragma unroll
        for (int am = 0; am < 4; ++am)
#pragma unroll
            for (int an = 0; an < 4; ++an)
                acc[am][an] = __builtin_amdgcn_mfma_f32_16x16x32_fp8_fp8(
                    a2[am][1], b2[an][1], acc[am][an], 0, 0, 0);
        __builtin_amdgcn_s_setprio(0);

        // end of tile: my ds_reads retired; tile t+1's DMAs (issued at t-1)
        // landed; t+2's batch (just issued) stays in flight.
        asm volatile("s_waitcnt lgkmcnt(0)" ::: "memory");
        if (t < NKT - 2)       asm volatile("s_waitcnt vmcnt(4)" ::: "memory");
        else if (t == NKT - 2) asm volatile("s_waitcnt vmcnt(0)" ::: "memory");
        __builtin_amdgcn_s_barrier();
    }

    // ---- epilogue: per-row max (diag excluded, scaled x128*sgn) + own ----
    const float NEG = -1e30f;
#pragma unroll
    for (int am = 0; am < 4; ++am) {
#pragma unroll
        for (int reg = 0; reg < 4; ++reg) {
            const int rl   = wm * 64 + am * 16 + hi * 4 + reg;
            const int rowg = r0 + rl;
            const int spk  = rowg >> 5;
            float m = NEG, o = NEG;
#pragma unroll
            for (int an = 0; an < 4; ++an) {
                const int col = n0 + wn * 64 + an * 16 + lo;
                const float v = acc[am][an][reg];
                const bool dg = (col == spk);
                o = dg ? v : o;
                m = fmaxf(m, dg ? NEG : v);
            }
#pragma unroll
            for (int mask = 1; mask < 16; mask <<= 1) {
                m = fmaxf(m, __shfl_xor(m, mask));
                o = fmaxf(o, __shfl_xor(o, mask));
            }
            if (lo == 0) {
                redm[wn][rl] = m;
                redo[wn][rl] = o;
            }
        }
    }
    __syncthreads();

    if (tid < 128) {
        const float mo = fmaxf(redm[0][tid], redm[1][tid]);
        maxo_part[(size_t)nt * NROWS + r0 + tid] = mo;
        if (nt == (mt >> 5)) {
            own_part[r0 + tid] = fmaxf(redo[0][tid], redo[1][tid]);
        }
    }
}

// ---- k3: per-row finish: combine 8 tile-maxes, sigmoid, loss/corr ----------
__global__ void __launch_bounds__(256) rowred_kernel(const float* __restrict__ maxo_part,
                                                     const float* __restrict__ own_part,
                                                     const float* __restrict__ lnw,
                                                     const float* __restrict__ lnb,
                                                     float* __restrict__ partsum) {
    const int r = blockIdx.x * 256 + threadIdx.x;
    const float lw = lnw[0], lb = lnb[0];
    const float sgn = (lw >= 0.f) ? 1.f : -1.f;
    const float alw = fabsf(lw);
    const float inv128 = 1.f / 128.f;

    float mo = maxo_part[r];
#pragma unroll
    for (int p = 1; p < NTILES; ++p)
        mo = fmaxf(mo, maxo_part[(size_t)p * NROWS + r]);
    const float O     = own_part[r];              // 128*sgn*(e.ck_own)
    const float t_own = sgn * O * inv128;
    const float ex    = (32.f * t_own - 1.f) * (1.f / 31.f);
    const float own_s = sigmoidf(lw * ex + lb);
    const float mo_s  = sigmoidf(alw * mo * inv128 + lb);
    float loss = 1.f - own_s + mo_s;
    float corr = (sgn * ex >= mo * inv128) ? 1.f : 0.f;

#pragma unroll
    for (int mask = 1; mask < 64; mask <<= 1) {
        loss += __shfl_xor(loss, mask);
        corr += __shfl_xor(corr, mask);
    }
    __shared__ float sl[4], sc[4];
    const int wv = threadIdx.x >> 6;
    if ((threadIdx.x & 63) == 0) { sl[wv] = loss; sc[wv] = corr; }
    __syncthreads();
    if (threadIdx.x == 0) {
        partsum[blockIdx.x]       = sl[0] + sl[1] + sl[2] + sl[3];
        partsum[128 + blockIdx.x] = sc[0] + sc[1] + sc[2] + sc[3];
    }
}

// ---- k4: final scalar reduce ----------------------------------------------
__global__ void __launch_bounds__(128) final_kernel(const float* __restrict__ partsum,
                                                    float* __restrict__ out) {
    const int t = threadIdx.x;
    float l = partsum[t];
    float c = partsum[128 + t];
#pragma unroll
    for (int mask = 1; mask < 64; mask <<= 1) {
        l += __shfl_xor(l, mask);
        c += __shfl_xor(c, mask);
    }
    __shared__ float sl[2], sc[2];
    if ((t & 63) == 0) { sl[t >> 6] = l; sc[t >> 6] = c; }
    __syncthreads();
    if (t == 0) {
        out[0] = (sl[0] + sl[1]) * (1.f / (float)NROWS);
        out[1] = (sc[0] + sc[1]) * (1.f / (float)NROWS);
    }
}

extern "C" void kernel_launch(void* const* d_in, const int* in_sizes, int n_in,
                              void* d_out, int out_size, void* d_ws, size_t ws_size,
                              hipStream_t stream) {
    (void)in_sizes; (void)n_in; (void)out_size; (void)ws_size;
    const float* emb = (const float*)d_in[0];
    const float* lnw = (const float*)d_in[3];
    const float* lnb = (const float*)d_in[4];
    float* out = (float*)d_out;

    char* ws = (char*)d_ws;
    char* e8  = ws;                                           // 16 MB
    char* ck8 = ws + (size_t)NROWS * D_DIM;                   // 512 KB
    float* maxo_part = (float*)(ck8 + (size_t)N_SPK * D_DIM); // 1 MB
    float* own_part  = (float*)((char*)maxo_part + (size_t)NTILES * NROWS * 4); // 128 KB
    float* partsum   = (float*)((char*)own_part + (size_t)NROWS * 4);           // 1 KB

    prep_kernel<<<N_SPK, 256, 0, stream>>>(emb, lnw, e8, ck8);
    gemm_kernel<<<NWG, 256, 0, stream>>>(e8, ck8, maxo_part, own_part);
    rowred_kernel<<<NROWS / 256, 256, 0, stream>>>(maxo_part, own_part, lnw, lnb, partsum);
    final_kernel<<<1, 128, 0, stream>>>(partsum, out);
}